// Round 6
// baseline (306.273 us; speedup 1.0000x reference)
//
#include <hip/hip_runtime.h>
#include <stdint.h>

#define NODES 100000
#define EDGES 1000000
#define HF 256
#define TILES2 (EDGES / 32)
#define NBINS (98 * 1024)  // 100352 >= NODES, = 98 scan blocks x 1024

// ws layout (sorted path):
//   [0, 256KB)            Bp: packed bf16 W1 B-fragments
//   [256KB, +102.4MB)     R[node][512] bf16 (P half has b1 folded in)
//   bins  int[NBINS]      hist -> exclusive offsets -> scatter cursors
//   part  int[128]        scan partials
//   rec   [EDGES][32B]    sorted {src,dst,oidx,pad, ef[8] bf16}

typedef short short8 __attribute__((ext_vector_type(8)));
typedef float f32x4 __attribute__((ext_vector_type(4)));
typedef float f32x2 __attribute__((ext_vector_type(2)));
typedef int i32x4 __attribute__((ext_vector_type(4)));

__device__ __forceinline__ unsigned short f2b(float f) {
  union { float f; uint32_t u; } v; v.f = f;
  return (unsigned short)((v.u + 0x7FFFu + ((v.u >> 16) & 1u)) >> 16);  // RNE
}
__device__ __forceinline__ float asf(uint32_t u) {
  union { uint32_t u; float f; } v; v.u = u;
  return v.f;
}
__device__ __forceinline__ float b2f(unsigned short s) {
  return asf(((uint32_t)s) << 16);
}
__device__ __forceinline__ uint32_t cvtpk(float lo, float hi) {
  uint32_t pk;
  asm("v_cvt_pk_bf16_f32 %0, %1, %2" : "=v"(pk) : "v"(lo), "v"(hi));
  return pk;
}

// ---------------- pack W1 rows 7..518 into MFMA B-fragment order (bf16) -------------
__global__ __launch_bounds__(256) void pack_w1(const float* __restrict__ W1,
                                               unsigned short* __restrict__ Bp) {
  int idx = blockIdx.x * 256 + threadIdx.x;  // 0..16383
  int lane = idx & 63;
  int nbg  = (idx >> 6) & 31;
  int kb   = idx >> 11;
  int n    = nbg * 16 + (lane & 15);
  int k0   = kb * 32 + (lane >> 4) * 8;
  int rbase = (n < 256) ? 7 : 263;
  int col   = n & 255;
  short8 o;
#pragma unroll
  for (int j = 0; j < 8; ++j)
    o[j] = (short)f2b(W1[(size_t)(rbase + k0 + j) * HF + col]);
  *reinterpret_cast<short8*>(Bp + (size_t)idx * 8) = o;
}

// ---------------- R = h @ Wcat (+b1 on P half)  (M=100000, K=256, N=512) -------------
__global__ __launch_bounds__(256, 1) void gemm_R(const float* __restrict__ h,
                                                 const unsigned short* __restrict__ Bp,
                                                 const float* __restrict__ b1,
                                                 unsigned short* __restrict__ R) {
  __shared__ unsigned short A[64][264];
  const int m0 = blockIdx.x * 64;
  const int t  = threadIdx.x;
  {
    const int r = t >> 2, q = t & 3;
    const int grow = m0 + r;
    const bool valid = grow < NODES;
    const float* hp = h + (size_t)grow * HF + q * 64;
#pragma unroll
    for (int cc = 0; cc < 8; ++cc) {
      float4 a, b;
      if (valid) {
        a = *reinterpret_cast<const float4*>(hp + cc * 8);
        b = *reinterpret_cast<const float4*>(hp + cc * 8 + 4);
      } else {
        a = make_float4(0.f, 0.f, 0.f, 0.f);
        b = a;
      }
      uint32_t o32[4];
      o32[0] = cvtpk(a.x, a.y);
      o32[1] = cvtpk(a.z, a.w);
      o32[2] = cvtpk(b.x, b.y);
      o32[3] = cvtpk(b.z, b.w);
      *reinterpret_cast<uint4*>(&A[r][q * 64 + cc * 8]) =
          make_uint4(o32[0], o32[1], o32[2], o32[3]);
    }
  }
  __syncthreads();

  const int wave = t >> 6, lane = t & 63;
  const int l15 = lane & 15, lhi = lane >> 4;
  const int nbg0 = wave * 8;  // 8 16-col groups per wave -> 128 cols
  f32x4 acc[4][8] = {};
#pragma unroll
  for (int kb = 0; kb < 8; ++kb) {
    short8 bfrag[8];
#pragma unroll
    for (int nb = 0; nb < 8; ++nb)
      bfrag[nb] = *reinterpret_cast<const short8*>(
          Bp + (((size_t)(kb * 32 + nbg0 + nb) * 64 + lane) * 8));
    short8 afrag[4];
#pragma unroll
    for (int mb = 0; mb < 4; ++mb)
      afrag[mb] = *reinterpret_cast<const short8*>(&A[mb * 16 + l15][kb * 32 + lhi * 8]);
#pragma unroll
    for (int mb = 0; mb < 4; ++mb)
#pragma unroll
      for (int nb = 0; nb < 8; ++nb)
        acc[mb][nb] = __builtin_amdgcn_mfma_f32_16x16x32_bf16(
            afrag[mb], bfrag[nb], acc[mb][nb], 0, 0, 0);
  }
  const int c0 = wave * 128 + l15;
  float b1v[8] = {};
  if (wave < 2) {
#pragma unroll
    for (int nb = 0; nb < 8; ++nb) b1v[nb] = b1[c0 + nb * 16];
  }
#pragma unroll
  for (int mb = 0; mb < 4; ++mb) {
#pragma unroll
    for (int i = 0; i < 4; ++i) {
      const int row = m0 + mb * 16 + lhi * 4 + i;
      if (row < NODES) {
        unsigned short* rp = R + (size_t)row * 512 + c0;
#pragma unroll
        for (int nb = 0; nb < 8; ++nb) rp[nb * 16] = f2b(acc[mb][nb][i] + b1v[nb]);
      }
    }
  }
}

// ---------------- counting sort by src: hist -> scan -> scatter ---------------------
__global__ __launch_bounds__(256) void hist_k(const int* __restrict__ src,
                                              int* __restrict__ bins) {
  int e = blockIdx.x * 256 + threadIdx.x;
  if (e < EDGES) atomicAdd(&bins[src[e]], 1);
}

__global__ __launch_bounds__(256) void scan_blocks(int* __restrict__ bins,
                                                   int* __restrict__ part) {
  __shared__ int sdata[256];
  const int t = threadIdx.x;
  const int base = blockIdx.x * 1024 + t * 4;
  int4 v = *reinterpret_cast<int4*>(bins + base);
  const int s = v.x + v.y + v.z + v.w;
  sdata[t] = s;
  __syncthreads();
#pragma unroll
  for (int off = 1; off < 256; off <<= 1) {
    int x = (t >= off) ? sdata[t - off] : 0;
    __syncthreads();
    sdata[t] += x;
    __syncthreads();
  }
  const int excl = sdata[t] - s;
  int4 o;
  o.x = excl; o.y = excl + v.x; o.z = o.y + v.y; o.w = o.z + v.z;
  *reinterpret_cast<int4*>(bins + base) = o;
  if (t == 255) part[blockIdx.x] = sdata[255];
}

__global__ __launch_bounds__(128) void scan_partials(int* __restrict__ part, int nb) {
  __shared__ int sdata[128];
  const int t = threadIdx.x;
  const int v = (t < nb) ? part[t] : 0;
  sdata[t] = v;
  __syncthreads();
#pragma unroll
  for (int off = 1; off < 128; off <<= 1) {
    int x = (t >= off) ? sdata[t - off] : 0;
    __syncthreads();
    sdata[t] += x;
    __syncthreads();
  }
  if (t < nb) part[t] = sdata[t] - v;  // exclusive
}

__global__ __launch_bounds__(256) void add_offsets(int* __restrict__ bins,
                                                   const int* __restrict__ part) {
  const int add = part[blockIdx.x];
  const int base = blockIdx.x * 1024 + threadIdx.x * 4;
  int4 v = *reinterpret_cast<int4*>(bins + base);
  v.x += add; v.y += add; v.z += add; v.w += add;
  *reinterpret_cast<int4*>(bins + base) = v;
}

__global__ __launch_bounds__(256) void scatter_k(const int* __restrict__ src,
                                                 const int* __restrict__ dst,
                                                 const float* __restrict__ ef,
                                                 int* __restrict__ bins,
                                                 char* __restrict__ rec) {
  int e = blockIdx.x * 256 + threadIdx.x;
  if (e >= EDGES) return;
  const int s = src[e];
  const int r = atomicAdd(&bins[s], 1);
  int4 meta;
  meta.x = s; meta.y = dst[e]; meta.z = e; meta.w = 0;
  short8 efp = {0, 0, 0, 0, 0, 0, 0, 0};
#pragma unroll
  for (int j = 0; j < 7; ++j) efp[j] = (short)f2b(ef[(size_t)e * 7 + j]);
  *reinterpret_cast<int4*>(rec + (size_t)r * 32) = meta;
  *reinterpret_cast<short8*>(rec + (size_t)r * 32 + 16) = efp;
}

// ---------------- per-edge MLP, 32 edges (2 MFMA tiles) per wave iteration -----------
// A-fragment layout: edge = lane&15, k-chunk = lane>>4 (R3 layout, no bpermute).
// SORTED: reads 32B rec (src-sorted), writes out[oidx] scattered.
template <bool SORTED>
__global__ __launch_bounds__(256) void edge_mlp(
    const unsigned short* __restrict__ R, const char* __restrict__ rec,
    const float* __restrict__ ef, const int* __restrict__ src,
    const int* __restrict__ dst, const float* __restrict__ W1,
    const float* __restrict__ W2, const float* __restrict__ b2,
    float* __restrict__ out) {
  __shared__ float w1a[7 * 256];
  for (int i = threadIdx.x; i < 7 * 64; i += 256)
    reinterpret_cast<float4*>(w1a)[i] = reinterpret_cast<const float4*>(W1)[i];
  __syncthreads();

  const int lane = threadIdx.x & 63;
  const int l15 = lane & 15, lhi = lane >> 4;

  // B fragment: W2 zero-padded to [256][16], bf16. lane holds B[kb*32+lhi*8+j][l15]
  short8 bfrag[8];
#pragma unroll
  for (int kb = 0; kb < 8; ++kb) {
    short8 b = {0, 0, 0, 0, 0, 0, 0, 0};
    if (l15 < 4) {
#pragma unroll
      for (int j = 0; j < 8; ++j)
        b[j] = (short)f2b(W2[(size_t)(kb * 32 + lhi * 8 + j) * 4 + l15]);
    }
    bfrag[kb] = b;
  }
  const float b2l = (l15 < 4) ? b2[l15] : 0.f;

  const int wid = (blockIdx.x * blockDim.x + threadIdx.x) >> 6;
  const int nw  = (gridDim.x * blockDim.x) >> 6;

#define TILE_KB(PV, QV, EFV, ACC)                                              \
  {                                                                            \
    const uint32_t* pu = reinterpret_cast<const uint32_t*>(&PV);               \
    const uint32_t* qu = reinterpret_cast<const uint32_t*>(&QV);               \
    f32x2 hd[4];                                                               \
    _Pragma("unroll") for (int w = 0; w < 4; ++w) {                            \
      f32x2 p2 = {asf(pu[w] << 16), asf(pu[w] & 0xffff0000u)};                 \
      f32x2 q2 = {asf(qu[w] << 16), asf(qu[w] & 0xffff0000u)};                 \
      hd[w] = p2 + q2;                                                         \
    }                                                                          \
    _Pragma("unroll") for (int j = 0; j < 7; ++j) {                            \
      f32x2 e2 = {EFV[j], EFV[j]};                                             \
      hd[0] = wv[j][0] * e2 + hd[0];                                           \
      hd[1] = wv[j][1] * e2 + hd[1];                                           \
      hd[2] = wv[j][2] * e2 + hd[2];                                           \
      hd[3] = wv[j][3] * e2 + hd[3];                                           \
    }                                                                          \
    union { i32x4 i; short8 s8; } afm;                                         \
    _Pragma("unroll") for (int w = 0; w < 4; ++w) {                            \
      const float lo = fmaxf(hd[w][0], 0.f);                                   \
      const float hi = fmaxf(hd[w][1], 0.f);                                   \
      afm.i[w] = (int)cvtpk(lo, hi);                                           \
    }                                                                          \
    ACC = __builtin_amdgcn_mfma_f32_16x16x32_bf16(afm.s8, bfrag[kb], ACC, 0, 0, 0); \
  }

  for (int t = wid; t < TILES2; t += nw) {
    const int e0 = t * 32;
    const int eiA = e0 + l15;
    const int eiB = eiA + 16;
    int sA, dA, sB, dB;
    float efA[7], efB[7];
    if constexpr (SORTED) {
      const int4 mA = *reinterpret_cast<const int4*>(rec + (size_t)eiA * 32);
      const int4 mB = *reinterpret_cast<const int4*>(rec + (size_t)eiB * 32);
      const short8 eA8 = *reinterpret_cast<const short8*>(rec + (size_t)eiA * 32 + 16);
      const short8 eB8 = *reinterpret_cast<const short8*>(rec + (size_t)eiB * 32 + 16);
      sA = mA.x; dA = mA.y; sB = mB.x; dB = mB.y;
#pragma unroll
      for (int j = 0; j < 7; ++j) {
        efA[j] = b2f((unsigned short)eA8[j]);
        efB[j] = b2f((unsigned short)eB8[j]);
      }
    } else {
      sA = src[eiA]; dA = dst[eiA];
      sB = src[eiB]; dB = dst[eiB];
#pragma unroll
      for (int j = 0; j < 7; ++j) {
        efA[j] = ef[(size_t)eiA * 7 + j];
        efB[j] = ef[(size_t)eiB * 7 + j];
      }
    }
    const unsigned short* PpA = R + (size_t)sA * 512 + lhi * 8;
    const unsigned short* QpA = R + (size_t)dA * 512 + 256 + lhi * 8;
    const unsigned short* PpB = R + (size_t)sB * 512 + lhi * 8;
    const unsigned short* QpB = R + (size_t)dB * 512 + 256 + lhi * 8;

    short8 pA[8], qA[8], pB[8], qB[8];
#pragma unroll
    for (int kb = 0; kb < 2; ++kb) {  // prime the pipeline, depth 2
      pA[kb] = *reinterpret_cast<const short8*>(PpA + kb * 32);
      qA[kb] = *reinterpret_cast<const short8*>(QpA + kb * 32);
      pB[kb] = *reinterpret_cast<const short8*>(PpB + kb * 32);
      qB[kb] = *reinterpret_cast<const short8*>(QpB + kb * 32);
    }

    f32x4 accA = {}, accB = {};
#pragma unroll
    for (int kb = 0; kb < 8; ++kb) {
      if (kb < 6) {  // rolling prefetch, static after unroll
        pA[kb + 2] = *reinterpret_cast<const short8*>(PpA + (kb + 2) * 32);
        qA[kb + 2] = *reinterpret_cast<const short8*>(QpA + (kb + 2) * 32);
        pB[kb + 2] = *reinterpret_cast<const short8*>(PpB + (kb + 2) * 32);
        qB[kb + 2] = *reinterpret_cast<const short8*>(QpB + (kb + 2) * 32);
      }
      f32x2 wv[7][4];
      const float* ws = w1a + kb * 32 + lhi * 8;
#pragma unroll
      for (int j = 0; j < 7; ++j) {
        const float4 wa = *reinterpret_cast<const float4*>(ws + j * 256);
        const float4 wb = *reinterpret_cast<const float4*>(ws + j * 256 + 4);
        wv[j][0] = {wa.x, wa.y};
        wv[j][1] = {wa.z, wa.w};
        wv[j][2] = {wb.x, wb.y};
        wv[j][3] = {wb.z, wb.w};
      }
      TILE_KB(pA[kb], qA[kb], efA, accA);
      TILE_KB(pB[kb], qB[kb], efB, accB);
    }
    // C layout: col = lane&15 (= output n), row = (lane>>4)*4 + i (= edge in tile)
    if (l15 < 4) {
#pragma unroll
      for (int i = 0; i < 4; ++i) {
        const int rA = e0 + lhi * 4 + i;
        const int rB = rA + 16;
        if constexpr (SORTED) {
          const int oA = *reinterpret_cast<const int*>(rec + (size_t)rA * 32 + 8);
          const int oB = *reinterpret_cast<const int*>(rec + (size_t)rB * 32 + 8);
          out[(size_t)oA * 4 + l15] = accA[i] + b2l;
          out[(size_t)oB * 4 + l15] = accB[i] + b2l;
        } else {
          out[(size_t)rA * 4 + l15] = accA[i] + b2l;
          out[(size_t)rB * 4 + l15] = accB[i] + b2l;
        }
      }
    }
  }
#undef TILE_KB
}

extern "C" void kernel_launch(void* const* d_in, const int* in_sizes, int n_in,
                              void* d_out, int out_size, void* d_ws, size_t ws_size,
                              hipStream_t stream) {
  const float* h  = (const float*)d_in[0];
  const float* ef = (const float*)d_in[1];
  const int* src  = (const int*)d_in[2];
  const int* dst  = (const int*)d_in[3];
  const float* W1 = (const float*)d_in[4];
  const float* b1 = (const float*)d_in[5];
  const float* W2 = (const float*)d_in[6];
  const float* b2 = (const float*)d_in[7];
  float* out = (float*)d_out;

  const size_t bp_bytes  = (size_t)8 * 32 * 64 * 8 * 2;   // 262144
  const size_t r_bytes   = (size_t)NODES * 512 * 2;       // 102,400,000
  const size_t bins_off  = bp_bytes + r_bytes;
  const size_t bins_bytes = (size_t)NBINS * 4;            // 401,408
  const size_t part_off  = bins_off + bins_bytes;
  const size_t rec_off   = part_off + 512;
  const size_t need      = rec_off + (size_t)EDGES * 32;  // ~135.1 MB

  unsigned short* Bp = (unsigned short*)d_ws;
  unsigned short* R  = (unsigned short*)((char*)d_ws + bp_bytes);

  pack_w1<<<64, 256, 0, stream>>>(W1, Bp);
  gemm_R<<<(NODES + 63) / 64, 256, 0, stream>>>(h, Bp, b1, R);

  if (ws_size >= need) {
    int*  bins = (int*)((char*)d_ws + bins_off);
    int*  part = (int*)((char*)d_ws + part_off);
    char* rec  = (char*)d_ws + rec_off;
    hipMemsetAsync(bins, 0, bins_bytes, stream);
    hist_k<<<(EDGES + 255) / 256, 256, 0, stream>>>(src, bins);
    scan_blocks<<<NBINS / 1024, 256, 0, stream>>>(bins, part);
    scan_partials<<<1, 128, 0, stream>>>(part, NBINS / 1024);
    add_offsets<<<NBINS / 1024, 256, 0, stream>>>(bins, part);
    scatter_k<<<(EDGES + 255) / 256, 256, 0, stream>>>(src, dst, ef, bins, rec);
    edge_mlp<true><<<2048, 256, 0, stream>>>(R, rec, ef, src, dst, W1, W2, b2, out);
  } else {
    edge_mlp<false><<<2048, 256, 0, stream>>>(R, nullptr, ef, src, dst, W1, W2, b2, out);
  }
}

// Round 8
// 293.626 us; speedup vs baseline: 1.0431x; 1.0431x over previous
//
#include <hip/hip_runtime.h>
#include <stdint.h>

#define NODES 100000
#define EDGES 1000000
#define HF 256
#define NBKT 32
#define BKT_NODES 3125   // NODES / NBKT
#define CAPMAX 33024     // mean 31250 + ~10 sigma, multiple of 32
#define GEMM_BLOCKS 1563 // ceil(NODES/64)
#define SCAT_BLOCKS 245  // ceil(EDGES/4096)
#define TILES2 (EDGES / 32)

// ws layout:
//   [0, 256KB)        Bp: packed bf16 W1 B-fragments
//   [256KB, +102.4MB) R[node][512] bf16 (P half = h@W1b + b1, Q half = h@W1c)
//   cursor int[32]    per-bucket scatter cursors (32B-slot units)
//   rec [NBKT*cap][32B] zero-filled; {src,dst,oidx+1,0} int4 + ef bf16 short8

typedef short short8 __attribute__((ext_vector_type(8)));
typedef float f32x4 __attribute__((ext_vector_type(4)));
typedef float f32x2 __attribute__((ext_vector_type(2)));
typedef int i32x4 __attribute__((ext_vector_type(4)));

__device__ __forceinline__ unsigned short f2b(float f) {
  union { float f; uint32_t u; } v; v.f = f;
  return (unsigned short)((v.u + 0x7FFFu + ((v.u >> 16) & 1u)) >> 16);  // RNE
}
__device__ __forceinline__ float asf(uint32_t u) {
  union { uint32_t u; float f; } v; v.u = u;
  return v.f;
}
__device__ __forceinline__ float b2f(unsigned short s) {
  return asf(((uint32_t)s) << 16);
}
__device__ __forceinline__ uint32_t cvtpk(float lo, float hi) {
  uint32_t pk;
  asm("v_cvt_pk_bf16_f32 %0, %1, %2" : "=v"(pk) : "v"(lo), "v"(hi));
  return pk;
}

// ============ k1: pack W1 rows 7..518 into MFMA B-frag order + cursor init ==========
__global__ __launch_bounds__(256) void pack_init(const float* __restrict__ W1,
                                                 unsigned short* __restrict__ Bp,
                                                 int* __restrict__ cursor, int cap) {
  if (blockIdx.x == 64) {
    if (cursor && threadIdx.x < NBKT) cursor[threadIdx.x] = threadIdx.x * cap;
    return;
  }
  int idx = blockIdx.x * 256 + threadIdx.x;  // 0..16383
  int lane = idx & 63;
  int nbg  = (idx >> 6) & 31;
  int kb   = idx >> 11;
  int n    = nbg * 16 + (lane & 15);
  int k0   = kb * 32 + (lane >> 4) * 8;
  int rbase = (n < 256) ? 7 : 263;
  int col   = n & 255;
  short8 o;
#pragma unroll
  for (int j = 0; j < 8; ++j)
    o[j] = (short)f2b(W1[(size_t)(rbase + k0 + j) * HF + col]);
  *reinterpret_cast<short8*>(Bp + (size_t)idx * 8) = o;
}

// ============ k2: gemm_R (blocks < GEMM_BLOCKS) fused with bucket-scatter ============
__global__ __launch_bounds__(256) void gemm_scatter(
    const float* __restrict__ h, const unsigned short* __restrict__ Bp,
    const float* __restrict__ b1, unsigned short* __restrict__ R,
    const int* __restrict__ src, const int* __restrict__ dst,
    const float* __restrict__ ef, int* __restrict__ cursor,
    uint4* __restrict__ rec, int pos_max) {
  __shared__ __align__(16) char sh[33792];
  const int t = threadIdx.x;

  if (blockIdx.x < GEMM_BLOCKS) {
    // ---------------- R = h @ Wcat (+b1 on P half), 64 rows x 512 cols ----------------
    unsigned short (*A)[264] = reinterpret_cast<unsigned short (*)[264]>(sh);
    const int m0 = blockIdx.x * 64;
    {
      const int r = t >> 2, q = t & 3;
      const int grow = m0 + r;
      const bool valid = grow < NODES;
      const float* hp = h + (size_t)grow * HF + q * 64;
#pragma unroll
      for (int cc = 0; cc < 8; ++cc) {
        float4 a, b;
        if (valid) {
          a = *reinterpret_cast<const float4*>(hp + cc * 8);
          b = *reinterpret_cast<const float4*>(hp + cc * 8 + 4);
        } else {
          a = make_float4(0.f, 0.f, 0.f, 0.f);
          b = a;
        }
        uint32_t o32[4];
        o32[0] = cvtpk(a.x, a.y);
        o32[1] = cvtpk(a.z, a.w);
        o32[2] = cvtpk(b.x, b.y);
        o32[3] = cvtpk(b.z, b.w);
        *reinterpret_cast<uint4*>(&A[r][q * 64 + cc * 8]) =
            make_uint4(o32[0], o32[1], o32[2], o32[3]);
      }
    }
    __syncthreads();

    const int wave = t >> 6, lane = t & 63;
    const int l15 = lane & 15, lhi = lane >> 4;
    const int nbg0 = wave * 8;
    f32x4 acc[4][8] = {};
#pragma unroll
    for (int kb = 0; kb < 8; ++kb) {
      short8 bfrag[8];
#pragma unroll
      for (int nb = 0; nb < 8; ++nb)
        bfrag[nb] = *reinterpret_cast<const short8*>(
            Bp + (((size_t)(kb * 32 + nbg0 + nb) * 64 + lane) * 8));
      short8 afrag[4];
#pragma unroll
      for (int mb = 0; mb < 4; ++mb)
        afrag[mb] = *reinterpret_cast<const short8*>(&A[mb * 16 + l15][kb * 32 + lhi * 8]);
#pragma unroll
      for (int mb = 0; mb < 4; ++mb)
#pragma unroll
        for (int nb = 0; nb < 8; ++nb)
          acc[mb][nb] = __builtin_amdgcn_mfma_f32_16x16x32_bf16(
              afrag[mb], bfrag[nb], acc[mb][nb], 0, 0, 0);
    }
    const int c0 = wave * 128 + l15;
    float b1v[8] = {};
    if (wave < 2) {
#pragma unroll
      for (int nb = 0; nb < 8; ++nb) b1v[nb] = b1[c0 + nb * 16];
    }
#pragma unroll
    for (int mb = 0; mb < 4; ++mb) {
#pragma unroll
      for (int i = 0; i < 4; ++i) {
        const int row = m0 + mb * 16 + lhi * 4 + i;
        if (row < NODES) {
          unsigned short* rp = R + (size_t)row * 512 + c0;
#pragma unroll
          for (int nb = 0; nb < 8; ++nb) rp[nb * 16] = f2b(acc[mb][nb][i] + b1v[nb]);
        }
      }
    }
  } else {
    // ---------------- bucket scatter: 4096 edges/block, LDS-aggregated -----------------
    int* cnt = reinterpret_cast<int*>(sh);            // [32][256]
    int* sbase = reinterpret_cast<int*>(sh + 32768);  // [32]
    const int blk = blockIdx.x - GEMM_BLOCKS;
    const int base_e = blk * 4096;
    const int nE = (base_e + 4096 <= EDGES) ? 4096 : (EDGES - base_e);
#pragma unroll
    for (int b = 0; b < NBKT; ++b) cnt[b * 256 + t] = 0;
    __syncthreads();
    // pass 1: per-thread per-bin counts (coalesced reads)
    for (int i = t; i < nE; i += 256) {
      const int s = src[base_e + i];
      cnt[(s / BKT_NODES) * 256 + t]++;
    }
    __syncthreads();
    // pass 2: per-bin exclusive scan over threads + global range reservation
    if (t < NBKT) {
      int run = 0;
#pragma unroll 4
      for (int j = 0; j < 256; ++j) {
        const int c = cnt[t * 256 + j];
        cnt[t * 256 + j] = run;
        run += c;
      }
      sbase[t] = atomicAdd(&cursor[t], run);
    }
    __syncthreads();
    // pass 3: write 32B records (cnt doubles as running per-thread cursor)
    for (int i = t; i < nE; i += 256) {
      const int e = base_e + i;
      const int s = src[e];
      const int b = s / BKT_NODES;
      int pos = sbase[b] + cnt[b * 256 + t]++;
      if (pos > pos_max) pos = pos_max;  // 10-sigma overflow insurance (stays in ws)
      uint4 meta;
      meta.x = (uint32_t)s;
      meta.y = (uint32_t)dst[e];
      meta.z = (uint32_t)(e + 1);  // validity flag: 0 = pad slot
      meta.w = 0u;
      short8 efp = {0, 0, 0, 0, 0, 0, 0, 0};
#pragma unroll
      for (int j = 0; j < 7; ++j) efp[j] = (short)f2b(ef[(size_t)e * 7 + j]);
      rec[(size_t)pos * 2] = meta;
      *reinterpret_cast<short8*>(rec + (size_t)pos * 2 + 1) = efp;
    }
  }
}

// ============ k3: per-edge MLP, 32 edges (2 MFMA tiles) per wave iteration ===========
// SORTED: plain grid-stride over nt_tot tiles of the zero-filled rec array.
// Pad slots: s=d=0 (valid R reads), flag=0 -> store skipped. No clamps, no cursor.
template <bool SORTED>
__global__ __launch_bounds__(256) void edge_mlp(
    const unsigned short* __restrict__ R, const uint4* __restrict__ rec,
    const float* __restrict__ ef, const int* __restrict__ src,
    const int* __restrict__ dst, const float* __restrict__ W1,
    const float* __restrict__ W2, const float* __restrict__ b2,
    float* __restrict__ out, int nt_tot) {
  __shared__ float w1a[7 * 256];
  for (int i = threadIdx.x; i < 7 * 64; i += 256)
    reinterpret_cast<float4*>(w1a)[i] = reinterpret_cast<const float4*>(W1)[i];
  __syncthreads();

  const int lane = threadIdx.x & 63;
  const int l15 = lane & 15, lhi = lane >> 4;

  short8 bfrag[8];
#pragma unroll
  for (int kb = 0; kb < 8; ++kb) {
    short8 b = {0, 0, 0, 0, 0, 0, 0, 0};
    if (l15 < 4) {
#pragma unroll
      for (int j = 0; j < 8; ++j)
        b[j] = (short)f2b(W2[(size_t)(kb * 32 + lhi * 8 + j) * 4 + l15]);
    }
    bfrag[kb] = b;
  }
  const float b2l = (l15 < 4) ? b2[l15] : 0.f;

  const int wid = (blockIdx.x * blockDim.x + threadIdx.x) >> 6;
  const int nw  = (gridDim.x * blockDim.x) >> 6;

#define TILE_KB(PV, QV, EFV, ACC)                                              \
  {                                                                            \
    const uint32_t* pu = reinterpret_cast<const uint32_t*>(&PV);               \
    const uint32_t* qu = reinterpret_cast<const uint32_t*>(&QV);               \
    f32x2 hd[4];                                                               \
    _Pragma("unroll") for (int w = 0; w < 4; ++w) {                            \
      f32x2 p2 = {asf(pu[w] << 16), asf(pu[w] & 0xffff0000u)};                 \
      f32x2 q2 = {asf(qu[w] << 16), asf(qu[w] & 0xffff0000u)};                 \
      hd[w] = p2 + q2;                                                         \
    }                                                                          \
    _Pragma("unroll") for (int j = 0; j < 7; ++j) {                            \
      f32x2 e2 = {EFV[j], EFV[j]};                                             \
      hd[0] = wv[j][0] * e2 + hd[0];                                           \
      hd[1] = wv[j][1] * e2 + hd[1];                                           \
      hd[2] = wv[j][2] * e2 + hd[2];                                           \
      hd[3] = wv[j][3] * e2 + hd[3];                                           \
    }                                                                          \
    union { i32x4 i; short8 s8; } afm;                                         \
    _Pragma("unroll") for (int w = 0; w < 4; ++w) {                            \
      const float lo = fmaxf(hd[w][0], 0.f);                                   \
      const float hi = fmaxf(hd[w][1], 0.f);                                   \
      afm.i[w] = (int)cvtpk(lo, hi);                                           \
    }                                                                          \
    ACC = __builtin_amdgcn_mfma_f32_16x16x32_bf16(afm.s8, bfrag[kb], ACC, 0, 0, 0); \
  }

#define BODY(STORE_A, STORE_B)                                                  \
  {                                                                             \
    const unsigned short* PpA = R + (size_t)sA * 512 + lhi * 8;                 \
    const unsigned short* QpA = R + (size_t)dA * 512 + 256 + lhi * 8;           \
    const unsigned short* PpB = R + (size_t)sB * 512 + lhi * 8;                 \
    const unsigned short* QpB = R + (size_t)dB * 512 + 256 + lhi * 8;           \
    short8 pA[8], qA[8], pB[8], qB[8];                                          \
    _Pragma("unroll") for (int kb = 0; kb < 2; ++kb) {                          \
      pA[kb] = *reinterpret_cast<const short8*>(PpA + kb * 32);                 \
      qA[kb] = *reinterpret_cast<const short8*>(QpA + kb * 32);                 \
      pB[kb] = *reinterpret_cast<const short8*>(PpB + kb * 32);                 \
      qB[kb] = *reinterpret_cast<const short8*>(QpB + kb * 32);                 \
    }                                                                           \
    f32x4 accA = {}, accB = {};                                                 \
    _Pragma("unroll") for (int kb = 0; kb < 8; ++kb) {                          \
      if (kb < 6) {                                                             \
        pA[kb + 2] = *reinterpret_cast<const short8*>(PpA + (kb + 2) * 32);     \
        qA[kb + 2] = *reinterpret_cast<const short8*>(QpA + (kb + 2) * 32);     \
        pB[kb + 2] = *reinterpret_cast<const short8*>(PpB + (kb + 2) * 32);     \
        qB[kb + 2] = *reinterpret_cast<const short8*>(QpB + (kb + 2) * 32);     \
      }                                                                         \
      f32x2 wv[7][4];                                                           \
      const float* ws = w1a + kb * 32 + lhi * 8;                                \
      _Pragma("unroll") for (int j = 0; j < 7; ++j) {                           \
        const float4 wa = *reinterpret_cast<const float4*>(ws + j * 256);       \
        const float4 wb = *reinterpret_cast<const float4*>(ws + j * 256 + 4);   \
        wv[j][0] = {wa.x, wa.y};                                                \
        wv[j][1] = {wa.z, wa.w};                                                \
        wv[j][2] = {wb.x, wb.y};                                                \
        wv[j][3] = {wb.z, wb.w};                                                \
      }                                                                         \
      TILE_KB(pA[kb], qA[kb], efA, accA);                                       \
      TILE_KB(pB[kb], qB[kb], efB, accB);                                       \
    }                                                                           \
    if (l15 < 4) {                                                              \
      _Pragma("unroll") for (int i = 0; i < 4; ++i) { STORE_A; STORE_B; }       \
    }                                                                           \
  }

  if constexpr (SORTED) {
    const uint32_t* rec32 = reinterpret_cast<const uint32_t*>(rec);
    for (int tt = wid; tt < nt_tot; tt += nw) {
      const int e0 = tt * 32;
      const int eiA = e0 + l15;
      const int eiB = eiA + 16;
      const uint4 ma = rec[(size_t)eiA * 2];
      const uint4 mb = rec[(size_t)eiB * 2];
      const short8 ea = *reinterpret_cast<const short8*>(rec + (size_t)eiA * 2 + 1);
      const short8 eb = *reinterpret_cast<const short8*>(rec + (size_t)eiB * 2 + 1);
      const int sA = (int)ma.x, dA = (int)ma.y;
      const int sB = (int)mb.x, dB = (int)mb.y;
      float efA[7], efB[7];
#pragma unroll
      for (int j = 0; j < 7; ++j) {
        efA[j] = b2f((unsigned short)ea[j]);
        efB[j] = b2f((unsigned short)eb[j]);
      }
      BODY(
        {
          const int rA = e0 + lhi * 4 + i;
          const uint32_t va = rec32[(size_t)rA * 8 + 2];
          if (va) out[(size_t)(va - 1) * 4 + l15] = accA[i] + b2l;
        },
        {
          const int rB = e0 + 16 + lhi * 4 + i;
          const uint32_t vb = rec32[(size_t)rB * 8 + 2];
          if (vb) out[(size_t)(vb - 1) * 4 + l15] = accB[i] + b2l;
        })
    }
  } else {
    for (int t = wid; t < TILES2; t += nw) {
      const int e0 = t * 32;
      const int eiA = e0 + l15;
      const int eiB = eiA + 16;
      const int sA = src[eiA], dA = dst[eiA];
      const int sB = src[eiB], dB = dst[eiB];
      float efA[7], efB[7];
#pragma unroll
      for (int j = 0; j < 7; ++j) {
        efA[j] = ef[(size_t)eiA * 7 + j];
        efB[j] = ef[(size_t)eiB * 7 + j];
      }
      BODY(
        { out[(size_t)(e0 + lhi * 4 + i) * 4 + l15] = accA[i] + b2l; },
        { out[(size_t)(e0 + 16 + lhi * 4 + i) * 4 + l15] = accB[i] + b2l; })
    }
  }
#undef BODY
#undef TILE_KB
}

extern "C" void kernel_launch(void* const* d_in, const int* in_sizes, int n_in,
                              void* d_out, int out_size, void* d_ws, size_t ws_size,
                              hipStream_t stream) {
  const float* h  = (const float*)d_in[0];
  const float* ef = (const float*)d_in[1];
  const int* src  = (const int*)d_in[2];
  const int* dst  = (const int*)d_in[3];
  const float* W1 = (const float*)d_in[4];
  const float* b1 = (const float*)d_in[5];
  const float* W2 = (const float*)d_in[6];
  const float* b2 = (const float*)d_in[7];
  float* out = (float*)d_out;

  const size_t bp_bytes = (size_t)8 * 32 * 64 * 8 * 2;   // 262144
  const size_t r_bytes  = (size_t)NODES * 512 * 2;       // 102,400,000
  const size_t cur_off  = bp_bytes + r_bytes;
  const size_t rec_off  = cur_off + 256;                 // 16B aligned

  // adaptive bucket capacity from available workspace (32B/slot, +64KB slack)
  int cap = 0;
  if (ws_size > rec_off + 65536) {
    size_t c = (ws_size - rec_off - 65536) / ((size_t)NBKT * 32);
    c &= ~(size_t)31;
    if (c > CAPMAX) c = CAPMAX;
    cap = (int)c;
  }

  unsigned short* Bp = (unsigned short*)d_ws;
  unsigned short* R  = (unsigned short*)((char*)d_ws + bp_bytes);

  if (cap >= 32000) {
    int*   cursor = (int*)((char*)d_ws + cur_off);
    uint4* rec    = (uint4*)((char*)d_ws + rec_off);
    const size_t rec_bytes = (size_t)NBKT * cap * 32;
    pack_init<<<65, 256, 0, stream>>>(W1, Bp, cursor, cap);
    hipMemsetAsync(rec, 0, rec_bytes + 65536, stream);
    gemm_scatter<<<GEMM_BLOCKS + SCAT_BLOCKS, 256, 0, stream>>>(
        h, Bp, b1, R, src, dst, ef, cursor, rec, NBKT * cap + 2047);
    edge_mlp<true><<<2048, 256, 0, stream>>>(R, rec, ef, src, dst, W1, W2, b2, out,
                                             NBKT * cap / 32);
  } else {
    pack_init<<<64, 256, 0, stream>>>(W1, Bp, nullptr, 0);
    gemm_scatter<<<GEMM_BLOCKS, 256, 0, stream>>>(
        h, Bp, b1, R, src, dst, ef, nullptr, nullptr, 0);
    edge_mlp<false><<<2048, 256, 0, stream>>>(R, nullptr, ef, src, dst, W1, W2, b2, out,
                                              0);
  }
}